// Round 7
// baseline (1459.121 us; speedup 1.0000x reference)
//
#include <hip/hip_runtime.h>

// ---------------------------------------------------------------------------
// MoE forward: gating MLP + 8 dense experts + gate-weighted combine.
// All matmuls via mfma_f32_16x16x32_f16 (fp32 accum).
// Gating/H GEMMs: r4-verified gemm256 (m201-style 8-phase, 2 barriers/phase).
// OUT GEMM: gemmO2 — BM=BN=128, BK=32, 4 LDS buffers (64KB -> 2 blocks/CU),
// 4 waves (64x64 wave tile, 16 MFMA : 8 ds_read per phase), register
// read-ahead (reads for tile t+1 issued before MFMA(t)), ONE barrier/phase,
// vmcnt(8) counted drain (2-phase lead). Pair-swizzled 64B rows
// (slot ^= pair&7), inverse applied on the global source (rule #21).
// ---------------------------------------------------------------------------

#define DI __device__ __forceinline__

typedef _Float16 f16;
typedef _Float16 f16x8 __attribute__((ext_vector_type(8)));
typedef float f32x4 __attribute__((ext_vector_type(4)));

constexpr int BSZ  = 8192;
constexpr int IND  = 1024;
constexpr int HID  = 4096;
constexpr int OUTD = 1024;
constexpr int NE   = 8;
constexpr int HGD  = 2048;

// ---------------- fp32 -> fp16 vectorized convert (8 elems/thread) ---------
__global__ __launch_bounds__(256) void conv_f32_f16_kernel(
    const float* __restrict__ in, f16* __restrict__ out)
{
    size_t i = ((size_t)blockIdx.x * 256 + threadIdx.x) * 8;
    const float4* p = (const float4*)(in + i);
    float4 a = p[0], b = p[1];
    f16x8 v = {(f16)a.x, (f16)a.y, (f16)a.z, (f16)a.w,
               (f16)b.x, (f16)b.y, (f16)b.z, (f16)b.w};
    *(f16x8*)(out + i) = v;
}

// ---- transpose+convert: W[K][N] f32 -> Wt[n*ldo + ko + k] f16 -------------
__global__ __launch_bounds__(256) void transpose_f32_f16_kernel(
    const float* __restrict__ W, f16* __restrict__ Wt, int K, int N,
    int ldo, int ko)
{
    __shared__ float t[64][65];
    int n0 = blockIdx.x * 64, k0 = blockIdx.y * 64;
    int tx = threadIdx.x & 63, ty = threadIdx.x >> 6;
#pragma unroll
    for (int i = 0; i < 16; i++) {
        int k = i * 4 + ty;
        t[k][tx] = W[(size_t)(k0 + k) * N + n0 + tx];
    }
    __syncthreads();
#pragma unroll
    for (int i = 0; i < 16; i++) {
        int n = i * 4 + ty;
        Wt[(size_t)(n0 + n) * ldo + ko + k0 + tx] = (f16)t[tx][n];
    }
}

// ---------------- async global->LDS (16B per lane, wave-uniform dest) ------
DI void gload_lds16(const void* g, void* l)
{
    typedef const __attribute__((address_space(1))) unsigned int as1_t;
    typedef __attribute__((address_space(3))) unsigned int as3_t;
    __builtin_amdgcn_global_load_lds(
        (as1_t*)(unsigned long long)(__SIZE_TYPE__)g,
        (as3_t*)(unsigned int)(__SIZE_TYPE__)l,
        16, 0, 0);
}

// sync building blocks (rule #18: sched_barrier after lgkmcnt before MFMA)
#define SYNC_HEAD                                                              \
    __builtin_amdgcn_sched_barrier(0);                                         \
    __builtin_amdgcn_s_barrier();                                              \
    asm volatile("s_waitcnt lgkmcnt(0)" ::: "memory");                         \
    __builtin_amdgcn_sched_barrier(0);
#define SYNC_HEAD_T8                                                           \
    __builtin_amdgcn_sched_barrier(0);                                         \
    asm volatile("s_waitcnt lgkmcnt(8)");                                      \
    __builtin_amdgcn_s_barrier();                                              \
    asm volatile("s_waitcnt lgkmcnt(0)" ::: "memory");                         \
    __builtin_amdgcn_sched_barrier(0);
#define SYNC_TAIL                                                              \
    __builtin_amdgcn_sched_barrier(0);                                         \
    __builtin_amdgcn_s_barrier();                                              \
    asm volatile("" ::: "memory");

// ---------------------------------------------------------------------------
// gemm256 (r4-verified): BM=256, BN=256, BK=64, 8 waves 2Mx4N.
// ---------------------------------------------------------------------------
template <bool RELU>
__global__ __launch_bounds__(512, 2) void gemm256_kernel(
    const f16* __restrict__ A, const f16* __restrict__ Bt,
    const float* __restrict__ bias, f16* __restrict__ Cptr,
    int M, int N, int K)
{
    constexpr int BM = 256, BN = 256, BK = 64;
    constexpr int AT = BM * BK * 2, BT = BN * BK * 2;
    __shared__ __align__(16) f16 sA[2][BM * BK];
    __shared__ __align__(16) f16 sB[2][BN * BK];
    const char* sAc = (const char*)sA;
    const char* sBc = (const char*)sB;

    const int tid = threadIdx.x, wid = tid >> 6, lane = tid & 63;
    const int wm = wid >> 2, wn = wid & 3;
    const int nwg = gridDim.x, bid = blockIdx.x;
    const int wg = (bid & 7) * (nwg >> 3) + (bid >> 3);
    const int gx = N / BN;
    const size_t bm = (size_t)(wg / gx) * BM;
    const size_t bn = (size_t)(wg % gx) * BN;

    f32x4 acc[8][4] = {};

    const int rho  = tid >> 3;
    const int slot = (((tid & 7) << 4) ^ (((tid >> 3) & 7) << 4));
    const f16* pA = A  + (bm + rho) * (size_t)K + (slot >> 1);
    const f16* pB = Bt + (bn + rho) * (size_t)K + (slot >> 1);

    auto stA = [&](int b, int q, int T) {
        gload_lds16(pA + ((size_t)q * 64) * K + (size_t)T * BK,
                    (char*)sAc + b * AT + q * 8192 + wid * 1024);
    };
    auto stB = [&](int b, int q, int T) {
        gload_lds16(pB + ((size_t)q * 64) * K + (size_t)T * BK,
                    (char*)sBc + b * BT + q * 8192 + wid * 1024);
    };

    int offA0[8], offB0[4];
#pragma unroll
    for (int f = 0; f < 8; f++) {
        int r = wm * 128 + f * 16 + (lane & 15);
        offA0[f] = r * 128 + ((((lane >> 4) << 4)) ^ ((r & 7) << 4));
    }
#pragma unroll
    for (int f = 0; f < 4; f++) {
        int r = wn * 64 + f * 16 + (lane & 15);
        offB0[f] = r * 128 + ((((lane >> 4) << 4)) ^ ((r & 7) << 4));
    }

    f16x8 av[4][2], bv0[2][2], bv1[2][2];

#define LDAQ(B, MH)                                                            \
    _Pragma("unroll") for (int f = 0; f < 4; f++)                              \
    _Pragma("unroll") for (int kc = 0; kc < 2; kc++)                           \
        av[f][kc] = *(const f16x8*)(sAc + (B) * AT + (offA0[(MH)*4+f] ^ (kc << 6)));
#define LDBH(B, NH, BV)                                                        \
    _Pragma("unroll") for (int f = 0; f < 2; f++)                              \
    _Pragma("unroll") for (int kc = 0; kc < 2; kc++)                           \
        BV[f][kc] = *(const f16x8*)(sBc + (B) * BT + (offB0[(NH)*2+f] ^ (kc << 6)));
#define QUAD(MH, NH, BV)                                                       \
    __builtin_amdgcn_s_setprio(1);                                             \
    _Pragma("unroll") for (int f = 0; f < 4; f++)                              \
    _Pragma("unroll") for (int g = 0; g < 2; g++)                              \
    _Pragma("unroll") for (int kc = 0; kc < 2; kc++)                           \
        acc[(MH)*4+f][(NH)*2+g] = __builtin_amdgcn_mfma_f32_16x16x32_f16(      \
            av[f][kc], BV[g][kc], acc[(MH)*4+f][(NH)*2+g], 0, 0, 0);           \
    __builtin_amdgcn_s_setprio(0);

    const int NT = K / BK, NI = NT / 2;

    stA(0,0,0); stA(0,2,0); stB(0,0,0); stB(0,1,0); stB(0,2,0); stB(0,3,0);
    stA(0,1,0); stA(0,3,0);
    stA(1,0,1); stA(1,2,1); stB(1,0,1); stB(1,1,1); stB(1,2,1); stB(1,3,1);
    asm volatile("s_waitcnt vmcnt(6)");
    __builtin_amdgcn_s_barrier();
    asm volatile("" ::: "memory");

    for (int i = 0; i < NI - 1; ++i) {
        const int t = 2 * i;
        LDAQ(0, 0) LDBH(0, 0, bv0)
        stA(1, 1, t + 1); stA(1, 3, t + 1);
        SYNC_HEAD_T8
        QUAD(0, 0, bv0)
        SYNC_TAIL
        LDBH(0, 1, bv1)
        stA(0, 0, t + 2); stA(0, 2, t + 2);
        SYNC_HEAD
        QUAD(0, 1, bv1)
        SYNC_TAIL
        LDAQ(0, 1)
        stB(0, 0, t + 2); stB(0, 1, t + 2);
        SYNC_HEAD
        QUAD(1, 1, bv1)
        SYNC_TAIL
        stB(0, 2, t + 2); stB(0, 3, t + 2);
        SYNC_HEAD
        QUAD(1, 0, bv0)
        asm volatile("s_waitcnt vmcnt(6)");
        SYNC_TAIL
        LDAQ(1, 0) LDBH(1, 0, bv0)
        stA(0, 1, t + 2); stA(0, 3, t + 2);
        SYNC_HEAD_T8
        QUAD(0, 0, bv0)
        SYNC_TAIL
        LDBH(1, 1, bv1)
        stA(1, 0, t + 3); stA(1, 2, t + 3);
        SYNC_HEAD
        QUAD(0, 1, bv1)
        SYNC_TAIL
        LDAQ(1, 1)
        stB(1, 0, t + 3); stB(1, 1, t + 3);
        SYNC_HEAD
        QUAD(1, 1, bv1)
        SYNC_TAIL
        stB(1, 2, t + 3); stB(1, 3, t + 3);
        SYNC_HEAD
        QUAD(1, 0, bv0)
        asm volatile("s_waitcnt vmcnt(6)");
        SYNC_TAIL
    }
    {   // final iteration (tiles NT-2, NT-1)
        LDAQ(0, 0) LDBH(0, 0, bv0)
        stA(1, 1, NT - 1); stA(1, 3, NT - 1);
        SYNC_HEAD_T8
        QUAD(0, 0, bv0)
        SYNC_TAIL
        LDBH(0, 1, bv1)
        SYNC_HEAD
        QUAD(0, 1, bv1)
        SYNC_TAIL
        LDAQ(0, 1)
        SYNC_HEAD
        QUAD(1, 1, bv1)
        SYNC_TAIL
        SYNC_HEAD
        QUAD(1, 0, bv0)
        asm volatile("s_waitcnt vmcnt(0)");
        SYNC_TAIL
        LDAQ(1, 0) LDBH(1, 0, bv0)
        SYNC_HEAD
        QUAD(0, 0, bv0)
        SYNC_TAIL
        LDBH(1, 1, bv1)
        SYNC_HEAD
        QUAD(0, 1, bv1)
        SYNC_TAIL
        LDAQ(1, 1)
        SYNC_HEAD
        QUAD(1, 1, bv1)
        SYNC_TAIL
        SYNC_HEAD
        QUAD(1, 0, bv0)
        SYNC_TAIL
    }
#undef LDAQ
#undef LDBH
#undef QUAD

    const size_t row0 = bm + (size_t)wm * 128;
    const int col0 = (int)bn + wn * 64;
    const int c0 = lane & 15, r0 = (lane >> 4) * 4;
#pragma unroll
    for (int fm = 0; fm < 8; fm++)
#pragma unroll
        for (int r = 0; r < 4; r++) {
            const size_t row = row0 + fm * 16 + r0 + r;
#pragma unroll
            for (int n = 0; n < 4; n++) {
                const size_t col = (size_t)col0 + n * 16 + c0;
                float v = acc[fm][n][r] + bias[col];
                if constexpr (RELU) v = fmaxf(v, 0.0f);
                Cptr[row * (size_t)N + col] = (f16)v;
            }
        }
}

// ---------------------------------------------------------------------------
// gemmO2: BM=128, BN=128, BK=32, 4 waves (2Mx2N, 64x64 wave tile),
// 4 LDS buffers (64KB), register read-ahead, 1 barrier/phase, vmcnt(8).
// Requires K % 128 == 0 (NT % 4 == 0, NT >= 8).
// ---------------------------------------------------------------------------

#define STGO(BB, TT) { stA(BB, 0, TT); stA(BB, 1, TT);                         \
                       stB(BB, 0, TT); stB(BB, 1, TT); }

#define RDO(B, RS)                                                             \
    _Pragma("unroll") for (int f = 0; f < 4; f++) {                            \
        av##RS[f] = *(const f16x8*)(sAc + (B) * 8192 + offA[f]);               \
        bv##RS[f] = *(const f16x8*)(sBc + (B) * 8192 + offB[f]);               \
    }

#define MMO(MS)                                                                \
    __builtin_amdgcn_s_setprio(1);                                             \
    _Pragma("unroll") for (int fa = 0; fa < 4; fa++)                           \
    _Pragma("unroll") for (int fb = 0; fb < 4; fb++)                           \
        acc[fa][fb] = __builtin_amdgcn_mfma_f32_16x16x32_f16(                  \
            av##MS[fa], bv##MS[fb], acc[fa][fb], 0, 0, 0);                     \
    __builtin_amdgcn_s_setprio(0);

#define PHO_FULL(T, B, RS, MS)                                                 \
  {                                                                            \
    STGO(((B) + 3) & 3, (T) + 3)                                               \
    asm volatile("s_waitcnt vmcnt(8)");                                        \
    __builtin_amdgcn_sched_barrier(0);                                         \
    __builtin_amdgcn_s_barrier();                                              \
    asm volatile("" ::: "memory");                                             \
    RDO(((B) + 1) & 3, RS)                                                     \
    __builtin_amdgcn_sched_barrier(0);                                         \
    MMO(MS)                                                                    \
    asm volatile("s_waitcnt lgkmcnt(0)" ::: "memory");                         \
    __builtin_amdgcn_sched_barrier(0);                                         \
  }

#define PHO_TAIL(B, RS, MS, VM)                                                \
  {                                                                            \
    asm volatile("s_waitcnt vmcnt(" #VM ")");                                  \
    __builtin_amdgcn_sched_barrier(0);                                         \
    __builtin_amdgcn_s_barrier();                                              \
    asm volatile("" ::: "memory");                                             \
    RDO(((B) + 1) & 3, RS)                                                     \
    __builtin_amdgcn_sched_barrier(0);                                         \
    MMO(MS)                                                                    \
    asm volatile("s_waitcnt lgkmcnt(0)" ::: "memory");                         \
    __builtin_amdgcn_sched_barrier(0);                                         \
  }

template <bool ACCUM>
__global__ __launch_bounds__(256, 2) void gemmO2_kernel(
    const f16* __restrict__ A, const f16* __restrict__ Bt,
    const float* __restrict__ bias, const float* __restrict__ gate,
    float* __restrict__ Cptr, int M, int N, int K)
{
    constexpr int BM = 128, BN = 128, BK = 32;
    __shared__ __align__(16) f16 sA[4][BM * BK];   // 4 x 8KB
    __shared__ __align__(16) f16 sB[4][BN * BK];   // 4 x 8KB
    const char* sAc = (const char*)sA;
    const char* sBc = (const char*)sB;

    const int tid = threadIdx.x, wid = tid >> 6, lane = tid & 63;
    const int wm = wid >> 1, wn = wid & 1;

    const int nwg = gridDim.x, bid = blockIdx.x;
    const int wg = (bid & 7) * (nwg >> 3) + (bid >> 3);
    const int gx = N / BN;
    const size_t bm = (size_t)(wg / gx) * BM;
    const size_t bn = (size_t)(wg % gx) * BN;

    f32x4 acc[4][4] = {};

    // stage source mapping (inverse pair-swizzle, rule #21):
    // thread t covers LDS 16B slot o = t*16 within a 4KB call region.
    // pair P = t>>3, phys slot sp = t&7, logical s = sp ^ (P&7);
    // row = P*2 + (s>>2), k-elem = (s&3)*8.
    const int sl  = (tid & 7) ^ ((tid >> 3) & 7);
    const int r0s = ((tid >> 3) << 1) + (sl >> 2);
    const int kel = (sl & 3) * 8;
    const f16* pA = A  + (bm + r0s) * (size_t)K + kel;
    const f16* pB = Bt + (bn + r0s) * (size_t)K + kel;

    auto stA = [&](int b, int q, int T) {
        gload_lds16(pA + ((size_t)q * 64) * K + (size_t)T * BK,
                    (char*)sAc + b * 8192 + q * 4096 + wid * 1024);
    };
    auto stB = [&](int b, int q, int T) {
        gload_lds16(pB + ((size_t)q * 64) * K + (size_t)T * BK,
                    (char*)sBc + b * 8192 + q * 4096 + wid * 1024);
    };

    // fragment read offsets: row r, kslot ks -> P=r>>1, s=((r&1)*4+ks)^(P&7),
    // off = P*128 + s*16  (2 lanes/bank for every wave read = conflict-free)
    int offA[4], offB[4];
    const int ks = lane >> 4;
#pragma unroll
    for (int f = 0; f < 4; f++) {
        int r = wm * 64 + f * 16 + (lane & 15);
        int P = r >> 1;
        offA[f] = P * 128 + ((((r & 1) << 2) | ks) ^ (P & 7)) * 16;
        r = wn * 64 + f * 16 + (lane & 15);
        P = r >> 1;
        offB[f] = P * 128 + ((((r & 1) << 2) | ks) ^ (P & 7)) * 16;
    }

    f16x8 av0[4], bv0[4], av1[4], bv1[4];
    const int NT = K / BK;   // 128 (K=4096); NT % 4 == 0

    // prologue: stage tiles 0,1,2 -> bufs 0,1,2; drain tile 0; read frags(0)
    STGO(0, 0) STGO(1, 1) STGO(2, 2)
    asm volatile("s_waitcnt vmcnt(8)");
    __builtin_amdgcn_s_barrier();
    asm volatile("" ::: "memory");
    RDO(0, 0)
    asm volatile("s_waitcnt lgkmcnt(0)" ::: "memory");
    __builtin_amdgcn_sched_barrier(0);

    for (int t = 0; t < NT - 4; t += 4) {
        PHO_FULL(t + 0, 0, 1, 0)
        PHO_FULL(t + 1, 1, 0, 1)
        PHO_FULL(t + 2, 2, 1, 0)
        PHO_FULL(t + 3, 3, 0, 1)
    }
    // phases NT-4 .. NT-1
    PHO_FULL(NT - 4, 0, 1, 0)      // stages NT-1; drains stage(NT-3)
    PHO_TAIL(1, 0, 1, 4)           // drains stage(NT-2); reads frags(NT-2)
    PHO_TAIL(2, 1, 0, 0)           // drains stage(NT-1); reads frags(NT-1)
    {   // final phase: MFMA only
        __builtin_amdgcn_s_barrier();
        asm volatile("" ::: "memory");
        MMO(1)
    }

    // epilogue: C/D layout col=lane&15, row=(lane>>4)*4+reg
    const size_t row0 = bm + (size_t)wm * 64;
    const int col0 = (int)bn + wn * 64;
    const int c0 = lane & 15, r0 = (lane >> 4) * 4;
#pragma unroll
    for (int fa = 0; fa < 4; fa++)
#pragma unroll
        for (int r = 0; r < 4; r++) {
            const size_t row = row0 + fa * 16 + r0 + r;
            const float g = gate[row * NE];
#pragma unroll
            for (int fb = 0; fb < 4; fb++) {
                const size_t col = (size_t)col0 + fb * 16 + c0;
                float v = (acc[fa][fb][r] + bias[col]) * g;
                float* p = Cptr + row * (size_t)N + col;
                *p = ACCUM ? (*p + v) : v;
            }
        }
}

// --------- gating head: logits = gh@gw2 + gb2, softmax -> gates fp32 -------
__global__ __launch_bounds__(256) void gate_softmax_kernel(
    const f16* __restrict__ gh, const float* __restrict__ gw2,
    const float* __restrict__ gb2, float* __restrict__ gates)
{
    const int row  = blockIdx.x * 4 + (threadIdx.x >> 6);
    const int lane = threadIdx.x & 63;
    const f16* r = gh + (size_t)row * HGD;
    float acc[NE] = {};
    for (int k = lane; k < HGD; k += 64) {
        float h = (float)r[k];
        const float* w = gw2 + (size_t)k * NE;
#pragma unroll
        for (int e = 0; e < NE; e++) acc[e] = fmaf(h, w[e], acc[e]);
    }
#pragma unroll
    for (int off = 32; off > 0; off >>= 1)
#pragma unroll
        for (int e = 0; e < NE; e++) acc[e] += __shfl_down(acc[e], off, 64);
    if (lane == 0) {
        float l[NE], m = -1e30f;
#pragma unroll
        for (int e = 0; e < NE; e++) { l[e] = acc[e] + gb2[e]; m = fmaxf(m, l[e]); }
        float s = 0.f;
#pragma unroll
        for (int e = 0; e < NE; e++) { l[e] = expf(l[e] - m); s += l[e]; }
        float inv = 1.0f / s;
#pragma unroll
        for (int e = 0; e < NE; e++) gates[(size_t)row * NE + e] = l[e] * inv;
    }
}

// ---------------------------------------------------------------------------
extern "C" void kernel_launch(void* const* d_in, const int* in_sizes, int n_in,
                              void* d_out, int out_size, void* d_ws, size_t ws_size,
                              hipStream_t stream)
{
    const float* x   = (const float*)d_in[0];
    const float* gw1 = (const float*)d_in[1];
    const float* gb1 = (const float*)d_in[2];
    const float* gw2 = (const float*)d_in[3];
    const float* gb2 = (const float*)d_in[4];
    const float* ew1 = (const float*)d_in[5];
    const float* eb1 = (const float*)d_in[6];
    const float* ew2 = (const float*)d_in[7];
    const float* eb2 = (const float*)d_in[8];
    float* out = (float*)d_out;

    // ws layout: gates(256KB) | x16(16MB) | wbuf(8MB) | hbuf(64MB, gh aliases)
    char* ws = (char*)d_ws;
    float* gates = (float*)ws;
    f16* x16  = (f16*)(ws + (256 << 10));
    f16* wbuf = x16 + (size_t)BSZ * IND;
    f16* hbuf = wbuf + (size_t)HID * IND;
    f16* gh   = hbuf;  // alias: gh fully consumed before first expert GEMM

    // 1) x -> fp16
    conv_f32_f16_kernel<<<(BSZ * IND) / (256 * 8), 256, 0, stream>>>(x, x16);

    // 2) gating GEMM1: gh = relu(x @ gw1 + gb1)   [M=8192,N=2048,K=1024]
    transpose_f32_f16_kernel<<<dim3(HGD / 64, IND / 64), 256, 0, stream>>>(
        gw1, wbuf, IND, HGD, IND, 0);
    gemm256_kernel<true>
        <<<(HGD / 256) * (BSZ / 256), 512, 0, stream>>>(
            x16, wbuf, gb1, gh, BSZ, HGD, IND);

    // 3) gating head + softmax -> gates
    gate_softmax_kernel<<<BSZ / 4, 256, 0, stream>>>(gh, gw2, gb2, gates);

    // 4) experts
    for (int e = 0; e < NE; e++) {
        // h = relu(x @ ew1[e] + eb1[e])   [M=8192,N=4096,K=1024]
        transpose_f32_f16_kernel<<<dim3(HID / 64, IND / 64), 256, 0, stream>>>(
            ew1 + (size_t)e * IND * HID, wbuf, IND, HID, IND, 0);
        gemm256_kernel<true>
            <<<(HID / 256) * (BSZ / 256), 512, 0, stream>>>(
                x16, wbuf, eb1 + (size_t)e * HID, hbuf, BSZ, HID, IND);

        // out (+)= gates[:,e] * (h @ ew2[e] + eb2[e])   [M=8192,N=1024,K=4096]
        transpose_f32_f16_kernel<<<dim3(OUTD / 64, HID / 64), 256, 0, stream>>>(
            ew2 + (size_t)e * HID * OUTD, wbuf, HID, OUTD, HID, 0);
        if (e == 0)
            gemmO2_kernel<false>
                <<<(OUTD / 128) * (BSZ / 128), 256, 0, stream>>>(
                    hbuf, wbuf, eb2 + (size_t)e * OUTD, gates + e, out,
                    BSZ, OUTD, HID);
        else
            gemmO2_kernel<true>
                <<<(OUTD / 128) * (BSZ / 128), 256, 0, stream>>>(
                    hbuf, wbuf, eb2 + (size_t)e * OUTD, gates + e, out,
                    BSZ, OUTD, HID);
    }
}